// Round 6
// baseline (77.373 us; speedup 1.0000x reference)
//
#include <hip/hip_runtime.h>

// Problem constants (fixed by reference setup_inputs)
#define BB 2
#define CC 8
#define HH 64
#define WW 2048
#define HALO 4             // (SEARCH-1)/2
#define TW 64              // tile width (threads x)
#define TH 4               // pixel row-PAIRS per block (threads y)
#define PH (TH*2)          // 8 pixel rows per block
#define LW (TW + 2*HALO)   // 72
#define LH (PH + 2*HALO)   // 16
#define THRESH_SCALE 0.024f  // 3 * 0.008

typedef float vf2 __attribute__((ext_vector_type(2)));
typedef int   vi2 __attribute__((ext_vector_type(2)));

// Counting identity (verified absmax=0 in R3/R4/R5): reference's
// top-9-smallest + threshold + nonzero-count<3 collapses to
//   out = (#{81 taps: d2 <= t^2} < 4)
//
// R6: attack the LDS pipe (binding at ~6.5 us/CU per R4/R5 evidence:
// occupancy 2x was neutral, so not latency-bound). Vertical 2-px sharing
// cuts ds_read_b128 per pixel 81 -> 45 (10 tap rows serve 2 pixels);
// tz tap-split (tz0: rows 0..4, tz1: rows 5..9) keeps per-thread packed
// VALU work identical to R4 and occupancy at 16 waves/CU.

__global__ __launch_bounds__(512) void medror_kernel(const float* __restrict__ x,
                                                     float* __restrict__ out) {
    // Interleaved float4 per tap -> one ds_read_b128; consecutive lanes
    // 16 B apart = 2 lanes/bank (free on gfx950, m136).
    __shared__ float4 lds[LH * LW];        // 16*72*16 = 18432 B
    __shared__ vi2    pcnt[2 * TW * TH];   // 256 px * 2 halves * 8 B = 4096 B

    const int tx = threadIdx.x;            // 0..63
    const int ty = threadIdx.y;            // 0..3  (pixel row-pair)
    const int tz = threadIdx.z;            // 0..1  (tap-row split; wave-uniform)
    const int tid = (tz * TH + ty) * TW + tx;   // 0..511

    const int b  = blockIdx.z;
    const int h0 = blockIdx.y * PH;
    const int w0 = blockIdx.x * TW;
    const int HWc = HH * WW;
    const float* xb = x + (size_t)b * CC * HWc;

    // Stage halo region of channels 2,3,4 into LDS (zero pad = jnp.pad)
    for (int idx = tid; idx < LH * LW; idx += 512) {
        const int r = idx / LW;
        const int c = idx - r * LW;
        const int h = h0 + r - HALO;
        const int w = w0 + c - HALO;
        float4 v = make_float4(0.f, 0.f, 0.f, 0.f);
        if ((unsigned)h < HH && (unsigned)w < WW) {
            const int off = h * WW + w;
            v.x = xb[2 * HWc + off];
            v.y = xb[3 * HWc + off];
            v.z = xb[4 * HWc + off];
        }
        lds[idx] = v;
    }
    __syncthreads();

    // Pixel pair: A at row h0+2ty, B directly below. Shared 10-row tap window.
    const int w = w0 + tx;
    const int offA = (h0 + 2 * ty) * WW + w;
    const int offB = offA + WW;

    const float tA0 = xb[0 * HWc + offA] * THRESH_SCALE;
    const float tA1 = xb[1 * HWc + offA] * THRESH_SCALE;
    const float tB0 = xb[0 * HWc + offB] * THRESH_SCALE;
    const float tB1 = xb[1 * HWc + offB] * THRESH_SCALE;
    vf2 t2A; t2A.x = tA0 * tA0; t2A.y = tA1 * tA1;   // d<=t <=> d2<=t^2
    vf2 t2B; t2B.x = tB0 * tB0; t2B.y = tB1 * tB1;
    vf2 pAx; pAx.x = xb[2 * HWc + offA]; pAx.y = xb[5 * HWc + offA];
    vf2 pAy; pAy.x = xb[3 * HWc + offA]; pAy.y = xb[6 * HWc + offA];
    vf2 pAz; pAz.x = xb[4 * HWc + offA]; pAz.y = xb[7 * HWc + offA];
    vf2 pBx; pBx.x = xb[2 * HWc + offB]; pBx.y = xb[5 * HWc + offB];
    vf2 pBy; pBy.x = xb[3 * HWc + offB]; pBy.y = xb[6 * HWc + offB];
    vf2 pBz; pBz.x = xb[4 * HWc + offB]; pBz.y = xb[7 * HWc + offB];

    vi2 cA = {0, 0}, cB = {0, 0};
    const int base = 2 * ty * LW + tx;     // window-top (row 0) local addr

#pragma unroll
    for (int r = 0; r < 5; ++r) {
        const int row = tz * 5 + r;        // 0..9 across the two tz halves
        const int rowbase = base + row * LW;
        // A's window = rows 0..8, B's = rows 1..9 (each tap read ONCE,
        // applied to both pixels except the two boundary rows).
        const bool hasA = !(tz == 1 && r == 4);   // excludes row 9
        const bool hasB = !(tz == 0 && r == 0);   // excludes row 0
#pragma unroll
        for (int dw = 0; dw < 9; ++dw) {
            const float4 nb = lds[rowbase + dw];
            if (hasA) {
                vf2 dx = pAx - nb.x, dy = pAy - nb.y, dz = pAz - nb.z;
                vf2 d2 = dx * dx + dy * dy + dz * dz;
                cA -= (d2 <= t2A);         // vector cmp: 0 / -1 per component
            }
            if (hasB) {
                vf2 dx = pBx - nb.x, dy = pBy - nb.y, dz = pBz - nb.z;
                vf2 d2 = dx * dx + dy * dy + dz * dz;
                cB -= (d2 <= t2B);
            }
        }
    }

    // Combine the two tap-halves of each pixel pair through LDS.
    const int pix = ty * TW + tx;
    if (tz == 1) { pcnt[pix] = cA; pcnt[TW * TH + pix] = cB; }
    __syncthreads();
    if (tz == 0) {
        const vi2 oA = pcnt[pix];
        const vi2 oB = pcnt[TW * TH + pix];
        const int a0 = cA.x + oA.x, a1 = cA.y + oA.y;
        const int b0 = cB.x + oB.x, b1 = cB.y + oB.y;
        out[((size_t)b * 2 + 0) * HWc + offA] = (a0 < 4) ? 1000.0f : -1000.0f;
        out[((size_t)b * 2 + 1) * HWc + offA] = (a1 < 4) ? 1000.0f : -1000.0f;
        out[((size_t)b * 2 + 0) * HWc + offB] = (b0 < 4) ? 1000.0f : -1000.0f;
        out[((size_t)b * 2 + 1) * HWc + offB] = (b1 < 4) ? 1000.0f : -1000.0f;
    }
}

extern "C" void kernel_launch(void* const* d_in, const int* in_sizes, int n_in,
                              void* d_out, int out_size, void* d_ws, size_t ws_size,
                              hipStream_t stream) {
    const float* x = (const float*)d_in[0];
    float* out = (float*)d_out;
    dim3 grid(WW / TW, HH / PH, BB);   // 32 x 8 x 2 = 512 blocks
    dim3 block(TW, TH, 2);             // 512 threads: 2 threads per pixel-pair
    medror_kernel<<<grid, block, 0, stream>>>(x, out);
}

// Round 7
// 65.849 us; speedup vs baseline: 1.1750x; 1.1750x over previous
//
#include <hip/hip_runtime.h>

// Problem constants (fixed by reference setup_inputs)
#define BB 2
#define CC 8
#define HH 64
#define WW 2048
#define HALO 4            // (SEARCH-1)/2
#define TW 32             // tile width  (threads x)  -- R7: halved for 2x block granularity
#define TH 4              // tile height (threads y), 1 pixel per thread
#define LW (TW + 2*HALO)  // 40
#define LH (TH + 2*HALO)  // 12
#define THRESH_SCALE 0.024f  // 3 * 0.008

typedef float vf2 __attribute__((ext_vector_type(2)));
typedef int   vi2 __attribute__((ext_vector_type(2)));

// Counting identity (verified absmax=0 in R3..R6): the reference's
// top-9-smallest + threshold + nonzero-count<3 collapses to
//   out = (#{81 taps: d2 <= t^2} < 4)
// because the center tap is always d2==0 (contributes to the top-9 but never
// to the nonzero count) and no other tap can be exactly 0 for these inputs.
//
// R7 evidence-driven shape: 1024-block configs beat 512-block configs by
// ~12 us at identical wave count and per-wave work (R4 vs R6) -- the timed
// window overlaps the harness's HBM-saturating ws-fill, so block-level
// pipelining of the serial front-end (param loads + staging) under
// contended global latency is what matters. Go finer: 2048 blocks x 128
// threads (8 blocks/CU), same 16 waves/CU, R4's exact lean inner loop.

__global__ __launch_bounds__(TW * TH) void medror_kernel(const float* __restrict__ x,
                                                         float* __restrict__ out) {
    // Interleaved float4 per tap: (ch2, ch3, ch4, pad) -> one ds_read_b128
    __shared__ float4 lds[LH * LW];   // 12*40*16 = 7680 B

    const int b  = blockIdx.z;
    const int h0 = blockIdx.y * TH;
    const int w0 = blockIdx.x * TW;
    const int tid = threadIdx.y * TW + threadIdx.x;   // 0..127
    const int HWc = HH * WW;

    const float* xb = x + (size_t)b * CC * HWc;

    // Stage halo region of channels 2,3,4 into LDS (zero pad = jnp.pad)
    for (int idx = tid; idx < LH * LW; idx += TW * TH) {
        const int r = idx / LW;
        const int c = idx - r * LW;
        const int h = h0 + r - HALO;
        const int w = w0 + c - HALO;
        float4 v = make_float4(0.f, 0.f, 0.f, 0.f);
        if ((unsigned)h < HH && (unsigned)w < WW) {
            const int off = h * WW + w;
            v.x = xb[2 * HWc + off];
            v.y = xb[3 * HWc + off];
            v.z = xb[4 * HWc + off];
        }
        lds[idx] = v;
    }
    __syncthreads();

    const int h = h0 + threadIdx.y;
    const int w = w0 + threadIdx.x;
    const int off = h * WW + w;

    // Pack the two echoes into lane-local 2-vectors -> v_pk_* dual-fp32 ops
    const float t0 = xb[0 * HWc + off] * THRESH_SCALE;
    const float t1 = xb[1 * HWc + off] * THRESH_SCALE;
    vf2 t2; t2.x = t0 * t0; t2.y = t1 * t1;   // sqrt(d2)<=t  <=>  d2<=t^2  (t>=0)
    vf2 px; px.x = xb[2 * HWc + off]; px.y = xb[5 * HWc + off];
    vf2 py; py.x = xb[3 * HWc + off]; py.y = xb[6 * HWc + off];
    vf2 pz; pz.x = xb[4 * HWc + off]; pz.y = xb[7 * HWc + off];

    vi2 cnt = {0, 0};   // #{taps: d2 <= t^2} per echo
    const int base = threadIdx.y * LW + threadIdx.x;   // tap (dh=-4, dw=-4)

#pragma unroll
    for (int dh = 0; dh < 9; ++dh) {
        const int rowbase = base + dh * LW;
#pragma unroll
        for (int dw = 0; dw < 9; ++dw) {
            const float4 nb = lds[rowbase + dw];
            vf2 dx = px - nb.x;
            vf2 dy = py - nb.y;
            vf2 dz = pz - nb.z;
            vf2 d2 = dx * dx + dy * dy + dz * dz;
            cnt -= (d2 <= t2);    // vector cmp yields 0 / -1 per component
        }
    }

    out[((size_t)b * 2 + 0) * HWc + off] = (cnt.x < 4) ? 1000.0f : -1000.0f;
    out[((size_t)b * 2 + 1) * HWc + off] = (cnt.y < 4) ? 1000.0f : -1000.0f;
}

extern "C" void kernel_launch(void* const* d_in, const int* in_sizes, int n_in,
                              void* d_out, int out_size, void* d_ws, size_t ws_size,
                              hipStream_t stream) {
    const float* x = (const float*)d_in[0];
    float* out = (float*)d_out;
    dim3 grid(WW / TW, HH / TH, BB);   // 64 x 16 x 2 = 2048 blocks (8 blocks/CU)
    dim3 block(TW, TH);                // 128 threads
    medror_kernel<<<grid, block, 0, stream>>>(x, out);
}

// Round 8
// 65.029 us; speedup vs baseline: 1.1898x; 1.0126x over previous
//
#include <hip/hip_runtime.h>

// Problem constants (fixed by reference setup_inputs)
#define BB 2
#define CC 8
#define HH 64
#define WW 2048
#define HALO 4            // (SEARCH-1)/2
#define TW 64             // tile width  (threads x)
#define TH 4              // tile height (threads y); 1 pixel per (tx,ty), 2 threads share it (tz)
#define LW (TW + 2*HALO)  // 72
#define LH (TH + 2*HALO)  // 12
#define THRESH_SCALE 0.024f  // 3 * 0.008

typedef float vf2 __attribute__((ext_vector_type(2)));
typedef int   vi2 __attribute__((ext_vector_type(2)));

// FINAL (best measured: 64.6 us, R5). Session findings:
//  - Counting identity (absmax=0 across R3..R7): reference's top-9-smallest
//    + threshold + nonzero-count<3 collapses to
//      out = (#{81 taps: d2 <= t^2} < 4)
//    (center tap is the only exact zero; sqrt removed via squared compare).
//  - Packed vf2 (dual-fp32 v_pk_*) for the two echoes: -19 us vs scalar+sqrt.
//  - Work-based levers are exhausted: occupancy 2x (R5), LDS instrs -45%
//    (R6), block granularity 2x (R7) all moved <=1.2 us around the plateau;
//    512-block shapes regress ~12 us. Timed window is dominated by the
//    harness's 268 MB d_ws re-poison (~42 us) + restore + dispatch.

__global__ __launch_bounds__(512, 8) void medror_kernel(const float* __restrict__ x,
                                                        float* __restrict__ out) {
    // Interleaved float4 per tap: (ch2, ch3, ch4, pad) -> one ds_read_b128,
    // consecutive lanes 16 B apart -> 2 lanes/bank (free on gfx950, m136).
    __shared__ float4 lds[LH * LW];       // 12*72*16 = 13824 B
    __shared__ vi2   pcnt[TW * TH];       // 256*8 = 2048 B partial counts

    const int tx = threadIdx.x;           // 0..63
    const int ty = threadIdx.y;           // 0..3
    const int tz = threadIdx.z;           // 0..1  (wave-uniform tap split)
    const int tid = (tz * TH + ty) * TW + tx;   // 0..511

    const int b  = blockIdx.z;
    const int h0 = blockIdx.y * TH;
    const int w0 = blockIdx.x * TW;
    const int HWc = HH * WW;

    const float* xb = x + (size_t)b * CC * HWc;

    // Stage halo region of channels 2,3,4 into LDS (zero pad = jnp.pad)
    for (int idx = tid; idx < LH * LW; idx += TW * TH * 2) {
        const int r = idx / LW;
        const int c = idx - r * LW;
        const int h = h0 + r - HALO;
        const int w = w0 + c - HALO;
        float4 v = make_float4(0.f, 0.f, 0.f, 0.f);
        if ((unsigned)h < HH && (unsigned)w < WW) {
            const int off = h * WW + w;
            v.x = xb[2 * HWc + off];
            v.y = xb[3 * HWc + off];
            v.z = xb[4 * HWc + off];
        }
        lds[idx] = v;
    }
    __syncthreads();

    const int w = w0 + tx;
    const int off = (h0 + ty) * WW + w;

    // Pack the two echoes into lane-local 2-vectors -> v_pk_* dual-fp32 ops
    const float t0 = xb[0 * HWc + off] * THRESH_SCALE;
    const float t1 = xb[1 * HWc + off] * THRESH_SCALE;
    vf2 t2; t2.x = t0 * t0; t2.y = t1 * t1;   // sqrt(d2)<=t  <=>  d2<=t^2  (t>=0)
    vf2 px; px.x = xb[2 * HWc + off]; px.y = xb[5 * HWc + off];
    vf2 py; py.x = xb[3 * HWc + off]; py.y = xb[6 * HWc + off];
    vf2 pz; pz.x = xb[4 * HWc + off]; pz.y = xb[7 * HWc + off];

    vi2 cnt = {0, 0};   // #{my taps: d2 <= t^2} per echo
    const int base = ty * LW + tx;        // tap (dh=0, dw=0) local addr

    // tz=0 owns tap rows 0..3 (36 taps); tz=1 owns rows 4..8 (45 taps).
    const int dh_lo = tz ? 4 : 0;
    const int dh_hi = tz ? 9 : 4;
    for (int dh = dh_lo; dh < dh_hi; ++dh) {
        const int rowbase = base + dh * LW;
#pragma unroll
        for (int dw = 0; dw < 9; ++dw) {
            const float4 nb = lds[rowbase + dw];
            vf2 dx = px - nb.x;
            vf2 dy = py - nb.y;
            vf2 dz = pz - nb.z;
            vf2 d2 = dx * dx + dy * dy + dz * dz;
            cnt -= (d2 <= t2);    // vector cmp yields 0 / -1 per component
        }
    }

    // Combine the two halves of each pixel through LDS.
    const int pix = ty * TW + tx;
    if (tz == 1) pcnt[pix] = cnt;
    __syncthreads();
    if (tz == 0) {
        const vi2 other = pcnt[pix];
        const int c0 = cnt.x + other.x;
        const int c1 = cnt.y + other.y;
        out[((size_t)b * 2 + 0) * HWc + off] = (c0 < 4) ? 1000.0f : -1000.0f;
        out[((size_t)b * 2 + 1) * HWc + off] = (c1 < 4) ? 1000.0f : -1000.0f;
    }
}

extern "C" void kernel_launch(void* const* d_in, const int* in_sizes, int n_in,
                              void* d_out, int out_size, void* d_ws, size_t ws_size,
                              hipStream_t stream) {
    const float* x = (const float*)d_in[0];
    float* out = (float*)d_out;
    dim3 grid(WW / TW, HH / TH, BB);   // 32 x 16 x 2 = 1024 blocks
    dim3 block(TW, TH, 2);             // 512 threads, 2 threads per pixel
    medror_kernel<<<grid, block, 0, stream>>>(x, out);
}